// Round 3
// baseline (2822.676 us; speedup 1.0000x reference)
//
#include <hip/hip_runtime.h>

#define B_ 2
#define T_ 2048
#define HID_ 2048
#define NK_ 16
#define DK_ 128
#define NV_ 32
#define DV_ 128
#define QKV_ 8192
#define VD_ 4096
#define QD_ 2048
#define MM (B_*T_)   // 4096
#define SV_ 256

typedef unsigned short u16;
typedef __attribute__((ext_vector_type(8))) unsigned short u16x8;
typedef __attribute__((ext_vector_type(8))) __bf16 bf16x8;
typedef __attribute__((ext_vector_type(4))) float f32x4;

__device__ inline u16 f2bf(float f) {
    unsigned int x = __float_as_uint(f);
    x += 0x7fffu + ((x >> 16) & 1u);   // round-to-nearest-even
    return (u16)(x >> 16);
}
__device__ inline float bf2f(u16 v) {
    return __uint_as_float(((unsigned int)v) << 16);
}

// ---------------- cast f32 -> bf16 (vectorized) ----------------
__global__ __launch_bounds__(256) void k_cast(const float* __restrict__ in,
                                              u16* __restrict__ out, int n4) {
    int i = blockIdx.x * 256 + threadIdx.x;
    if (i >= n4) return;
    float4 v = ((const float4*)in)[i];
    ((ushort4*)out)[i] = make_ushort4(f2bf(v.x), f2bf(v.y), f2bf(v.z), f2bf(v.w));
}

// ---------------- bf16 MFMA GEMM: C[M,N] = A[M,K] * B[N,K]^T ----------------
// OUT_BF16: 1 -> u16 output, 0 -> f32 output
template <int OUT_BF16>
__global__ __launch_bounds__(256) void k_gemm_bt(const u16* __restrict__ A,
                                                 const u16* __restrict__ Bm,
                                                 void* __restrict__ Cv,
                                                 int M, int N, int K) {
    __shared__ __align__(16) u16 As[128 * 72];
    __shared__ __align__(16) u16 Bs[128 * 72];
    int nbx = N >> 7;
    int bx = blockIdx.x % nbx, by = blockIdx.x / nbx;
    int brow = by << 7, bcol = bx << 7;
    int tid = threadIdx.x, lane = tid & 63, w = tid >> 6;
    int wr = (w >> 1) << 6, wc = (w & 1) << 6;
    int srow = tid >> 1, scol = (tid & 1) << 5;

    const u16* ag = A + (size_t)(brow + srow) * K + scol;
    const u16* bg = Bm + (size_t)(bcol + srow) * K + scol;
    u16* asw = &As[srow * 72 + scol];
    u16* bsw = &Bs[srow * 72 + scol];

    f32x4 acc[4][4];
#pragma unroll
    for (int m = 0; m < 4; m++)
#pragma unroll
        for (int n = 0; n < 4; n++) acc[m][n] = (f32x4){0.f, 0.f, 0.f, 0.f};

    int lrow = lane & 15, khalf = (lane >> 4) * 8;

    for (int kt = 0; kt < K; kt += 64) {
#pragma unroll
        for (int u = 0; u < 4; ++u) {
            *(u16x8*)(asw + u * 8) = *(const u16x8*)(ag + kt + u * 8);
            *(u16x8*)(bsw + u * 8) = *(const u16x8*)(bg + kt + u * 8);
        }
        __syncthreads();
#pragma unroll
        for (int kk = 0; kk < 64; kk += 32) {
            bf16x8 af[4], bfr[4];
#pragma unroll
            for (int m = 0; m < 4; m++)
                af[m] = *(const bf16x8*)&As[(wr + m * 16 + lrow) * 72 + kk + khalf];
#pragma unroll
            for (int n = 0; n < 4; n++)
                bfr[n] = *(const bf16x8*)&Bs[(wc + n * 16 + lrow) * 72 + kk + khalf];
#pragma unroll
            for (int m = 0; m < 4; m++)
#pragma unroll
                for (int n = 0; n < 4; n++)
                    acc[m][n] = __builtin_amdgcn_mfma_f32_16x16x32_bf16(af[m], bfr[n], acc[m][n], 0, 0, 0);
        }
        __syncthreads();
    }
    // C/D layout: col = lane&15, row = (lane>>4)*4 + r
    int crow = brow + wr + (lane >> 4) * 4;
    int ccol = bcol + wc + lrow;
#pragma unroll
    for (int m = 0; m < 4; m++)
#pragma unroll
        for (int n = 0; n < 4; n++) {
            if (OUT_BF16) {
                u16* cp = (u16*)Cv + (size_t)(crow + m * 16) * N + ccol + n * 16;
#pragma unroll
                for (int r = 0; r < 4; r++) cp[(size_t)r * N] = f2bf(acc[m][n][r]);
            } else {
                float* cp = (float*)Cv + (size_t)(crow + m * 16) * N + ccol + n * 16;
#pragma unroll
                for (int r = 0; r < 4; r++) cp[(size_t)r * N] = acc[m][n][r];
            }
        }
}

// ---------------- beta / decay (fp32 exact) ----------------
__global__ __launch_bounds__(256) void k_bd(const float* __restrict__ x,
                                            const float* __restrict__ Wb,
                                            const float* __restrict__ Wa,
                                            const float* __restrict__ dtb,
                                            const float* __restrict__ Alog,
                                            float* __restrict__ beta,
                                            float* __restrict__ decay) {
    int h2 = threadIdx.x & 63;
    int bt = blockIdx.x * 4 + (threadIdx.x >> 6);
    const float* xr = x + (size_t)bt * HID_;
    const float* W = (h2 < NV_) ? (Wb + (size_t)h2 * HID_) : (Wa + (size_t)(h2 - NV_) * HID_);
    float acc = 0.f;
    for (int kk = 0; kk < HID_; kk += 4) {
        float4 xv = *(const float4*)&xr[kk];
        float4 wv = *(const float4*)&W[kk];
        acc += xv.x * wv.x + xv.y * wv.y + xv.z * wv.z + xv.w * wv.w;
    }
    if (h2 < NV_) {
        beta[(size_t)bt * NV_ + h2] = 1.f / (1.f + expf(-acc));
    } else {
        int hh = h2 - NV_;
        float a = acc + dtb[hh];
        float sp = (a > 20.f) ? a : log1pf(expf(a));
        decay[(size_t)bt * NV_ + hh] = expf(-sp * expf(Alog[hh]));
    }
}

// ---------------- causal depthwise conv (KC=4) + q/k l2norm ----------------
__global__ __launch_bounds__(128) void k_conv_norm(const u16* __restrict__ qkv,
                                                   const float* __restrict__ conv_w,
                                                   u16* __restrict__ qn,
                                                   u16* __restrict__ kn,
                                                   u16* __restrict__ vv) {
    int g = blockIdx.x & 63;          // channel group of 128
    int bt = blockIdx.x >> 6;         // b*T + t
    int t = bt & (T_ - 1);
    int ch = (g << 7) + threadIdx.x;  // 0..8191
    float4 wv = *(const float4*)&conv_w[(size_t)ch << 2];
    const u16* col = qkv + (size_t)(bt - t) * QKV_ + ch;  // batch base
    float s = bf2f(col[(size_t)t * QKV_]) * wv.w;
    if (t >= 1) s += bf2f(col[(size_t)(t - 1) * QKV_]) * wv.z;
    if (t >= 2) s += bf2f(col[(size_t)(t - 2) * QKV_]) * wv.y;
    if (t >= 3) s += bf2f(col[(size_t)(t - 3) * QKV_]) * wv.x;

    if (g < 32) {
        float ss = s * s;
#pragma unroll
        for (int m = 1; m < 64; m <<= 1) ss += __shfl_xor(ss, m);
        __shared__ float red[2];
        if ((threadIdx.x & 63) == 0) red[threadIdx.x >> 6] = ss;
        __syncthreads();
        float tot = red[0] + red[1];
        float sc = 1.f / fmaxf(sqrtf(tot), 1e-12f);
        float o = s * sc;
        if (g < 16) qn[((size_t)bt * NK_ + g) * DK_ + threadIdx.x] = f2bf(o);
        else        kn[((size_t)bt * NK_ + (g - 16)) * DK_ + threadIdx.x] = f2bf(o);
    } else {
        vv[((size_t)bt * NV_ + (g - 32)) * DV_ + threadIdx.x] = f2bf(s);
    }
}

// ---------------- new_conv_buf output ----------------
__global__ __launch_bounds__(256) void k_convbuf(const u16* __restrict__ qkv,
                                                 float* __restrict__ ob) {
    int idx = blockIdx.x * 256 + threadIdx.x;
    if (idx >= B_ * QKV_ * 3) return;
    int jj = idx % 3;
    int d = (idx / 3) & (QKV_ - 1);
    int b = idx / (3 * QKV_);
    ob[idx] = bf2f(qkv[((size_t)b * T_ + (T_ - 3 + jj)) * QKV_ + d]);
}

// ---------------- recurrent delta-rule scan ----------------
// grid: (b, h, cg) = 2*16*8 blocks; block 256 threads.
// thread: cl = tid>>3 (column within 32-col group), oi = tid&7 (16-row slice).
__global__ __launch_bounds__(256) void k_scan(const u16* __restrict__ qn,
                                              const u16* __restrict__ kn,
                                              const u16* __restrict__ vv,
                                              const float* __restrict__ beta,
                                              const float* __restrict__ decay,
                                              float* __restrict__ attn,
                                              float* __restrict__ Sout) {
    int cg = blockIdx.x & 7;
    int h = (blockIdx.x >> 3) & 15;
    int b = blockIdx.x >> 7;
    int tid = threadIdx.x;
    int cl = tid >> 3;      // 0..31
    int oi = tid & 7;       // 0..7
    int i0 = oi << 4;
    int c = (cg << 5) + cl; // 0..255 state column
    int p = c >> 7;         // block-uniform (32-col group never straddles 128)
    int j = c & 127;
    int nv = (h << 1) + p;

    // stride-20 swizzle: 8 distinct ds_read_b128 addresses spread over all 32 banks
    __shared__ __align__(16) float sk[2][160];
    __shared__ __align__(16) float sq[2][160];
    __shared__ __align__(16) float sv[2][32];

    float S[16];
#pragma unroll
    for (int ii = 0; ii < 16; ++ii) S[ii] = 0.f;

    const size_t bT = (size_t)b * T_;
    // stage t=0
    if (tid < 128) sk[0][(tid >> 4) * 20 + (tid & 15)] = bf2f(kn[((bT) * NK_ + h) * DK_ + tid]);
    else { int q_ = tid - 128; sq[0][(q_ >> 4) * 20 + (q_ & 15)] = bf2f(qn[((bT) * NK_ + h) * DK_ + q_]); }
    if (tid < 32) sv[0][tid] = bf2f(vv[((bT) * NV_ + nv) * DV_ + ((cg & 3) << 5) + tid]);
    __syncthreads();

    int buf = 0;
    for (int t = 0; t < T_; ++t) {
        float kreg[16], qreg[16];
        const float4* k4 = (const float4*)&sk[buf][oi * 20];
        const float4* q4 = (const float4*)&sq[buf][oi * 20];
#pragma unroll
        for (int u = 0; u < 4; ++u) {
            float4 kv = k4[u], qv = q4[u];
            kreg[u * 4 + 0] = kv.x; kreg[u * 4 + 1] = kv.y; kreg[u * 4 + 2] = kv.z; kreg[u * 4 + 3] = kv.w;
            qreg[u * 4 + 0] = qv.x; qreg[u * 4 + 1] = qv.y; qreg[u * 4 + 2] = qv.z; qreg[u * 4 + 3] = qv.w;
        }
        float vval = sv[buf][cl];
        float bt_s = beta[(bT + t) * NV_ + nv];
        float dc_s = decay[(bT + t) * NV_ + nv];

        float skp = 0.f;
#pragma unroll
        for (int ii = 0; ii < 16; ++ii) skp += kreg[ii] * S[ii];
        skp += __shfl_xor(skp, 1);
        skp += __shfl_xor(skp, 2);
        skp += __shfl_xor(skp, 4);

        float dv = bt_s * (vval - skp);
        float op = 0.f;
#pragma unroll
        for (int ii = 0; ii < 16; ++ii) {
            float sn = S[ii] * dc_s + kreg[ii] * dv;
            S[ii] = sn;
            op += qreg[ii] * sn;
        }
        op += __shfl_xor(op, 1);
        op += __shfl_xor(op, 2);
        op += __shfl_xor(op, 4);

        int tn = t + 1;
        if (tn < T_) {
            int nb = buf ^ 1;
            if (tid < 128) sk[nb][(tid >> 4) * 20 + (tid & 15)] = bf2f(kn[((bT + tn) * NK_ + h) * DK_ + tid]);
            else { int q_ = tid - 128; sq[nb][(q_ >> 4) * 20 + (q_ & 15)] = bf2f(qn[((bT + tn) * NK_ + h) * DK_ + q_]); }
            if (tid < 32) sv[nb][tid] = bf2f(vv[((bT + tn) * NV_ + nv) * DV_ + ((cg & 3) << 5) + tid]);
        }
        if (oi == 0) attn[((bT + t) * NV_ + nv) * DV_ + j] = op;
        __syncthreads();
        buf ^= 1;
    }
#pragma unroll
    for (int ii = 0; ii < 16; ++ii)
        Sout[(((size_t)b * NK_ + h) * DK_ + (i0 + ii)) * SV_ + c] = S[ii];
}

// ---------------- RMSNorm + silu(z) gate -> bf16 ----------------
__global__ __launch_bounds__(256) void k_rms_silu(const float* __restrict__ attn,
                                                  const u16* __restrict__ z,
                                                  const float* __restrict__ norm_w,
                                                  u16* __restrict__ ofuse) {
    int w = threadIdx.x >> 6, lane = threadIdx.x & 63;
    size_t hm = (size_t)blockIdx.x * 4 + w;  // (b*T+t)*NV + nv
    const float* row = attn + hm * DV_;
    float2 v = *(const float2*)&row[lane * 2];
    float ss = v.x * v.x + v.y * v.y;
#pragma unroll
    for (int m = 1; m < 64; m <<= 1) ss += __shfl_xor(ss, m);
    float rms = rsqrtf(ss * (1.f / DV_) + 1e-6f);
    float2 nw = *(const float2*)&norm_w[lane * 2];
    size_t idx = hm * DV_ + lane * 2;
    ushort2 zv2 = *(const ushort2*)&z[idx];
    float z0 = bf2f(zv2.x), z1 = bf2f(zv2.y);
    float s0 = z0 / (1.f + expf(-z0));
    float s1 = z1 / (1.f + expf(-z1));
    *(ushort2*)&ofuse[idx] = make_ushort2(f2bf(v.x * rms * nw.x * s0),
                                          f2bf(v.y * rms * nw.y * s1));
}

extern "C" void kernel_launch(void* const* d_in, const int* in_sizes, int n_in,
                              void* d_out, int out_size, void* d_ws, size_t ws_size,
                              hipStream_t stream) {
    const float* x     = (const float*)d_in[0];
    const float* Wqkv  = (const float*)d_in[1];
    const float* Wz    = (const float*)d_in[2];
    const float* Wb    = (const float*)d_in[3];
    const float* Wa    = (const float*)d_in[4];
    const float* convw = (const float*)d_in[5];
    const float* dtb   = (const float*)d_in[6];
    const float* Alog  = (const float*)d_in[7];
    const float* normw = (const float*)d_in[8];
    const float* Wout  = (const float*)d_in[9];
    float* out = (float*)d_out;

    // ---- static workspace plan, 192 MB total, lifetime-aliased ----
    // [0,16)    x_bf     : cast -> GEMM2
    // [16,48)   Wqkv_bf  : cast -> GEMM1
    //           vv       : conv -> scan        (after GEMM1)
    //           Wout_bf  : [16,32) cast(after scan) -> GEMM3
    // [48,64)   Wz_bf    : cast -> GEMM2
    //           beta/decay [48,49) : k_bd(after GEMM2) -> scan
    // [64,128)  qkv_bf   : GEMM1 -> conv/convbuf
    //           attn     : scan -> rms
    // [128,160) z_bf     : GEMM2 -> rms
    // [160,192) qn[160,176) kn[176,192) : conv -> scan
    //           ofuse    : rms -> GEMM3
    char* ws = (char*)d_ws;
    u16*   x_bf    = (u16*)(ws + ((size_t)0 << 20));
    u16*   Wqkv_bf = (u16*)(ws + ((size_t)16 << 20));
    u16*   vv      = (u16*)(ws + ((size_t)16 << 20));
    u16*   Wout_bf = (u16*)(ws + ((size_t)16 << 20));
    u16*   Wz_bf   = (u16*)(ws + ((size_t)48 << 20));
    float* beta    = (float*)(ws + ((size_t)48 << 20));
    float* decay   = (float*)(ws + ((size_t)48 << 20) + (1 << 19));
    u16*   qkv_bf  = (u16*)(ws + ((size_t)64 << 20));
    float* attn    = (float*)(ws + ((size_t)64 << 20));
    u16*   z_bf    = (u16*)(ws + ((size_t)128 << 20));
    u16*   qn      = (u16*)(ws + ((size_t)160 << 20));
    u16*   kn      = (u16*)(ws + ((size_t)176 << 20));
    u16*   ofuse   = (u16*)(ws + ((size_t)160 << 20));

    float* y_out = out;
    float* S_out = out + (size_t)MM * HID_;
    float* cbuf  = S_out + (size_t)B_ * NK_ * DK_ * SV_;

    k_cast<<<dim3((MM * HID_ / 4 + 255) / 256), 256, 0, stream>>>(x, x_bf, MM * HID_ / 4);
    k_cast<<<dim3((QKV_ * HID_ / 4 + 255) / 256), 256, 0, stream>>>(Wqkv, Wqkv_bf, QKV_ * HID_ / 4);
    k_cast<<<dim3((VD_ * HID_ / 4 + 255) / 256), 256, 0, stream>>>(Wz, Wz_bf, VD_ * HID_ / 4);

    k_gemm_bt<1><<<dim3((MM / 128) * (QKV_ / 128)), 256, 0, stream>>>(x_bf, Wqkv_bf, qkv_bf, MM, QKV_, HID_);
    k_gemm_bt<1><<<dim3((MM / 128) * (VD_ / 128)), 256, 0, stream>>>(x_bf, Wz_bf, z_bf, MM, VD_, HID_);

    // beta/decay after GEMM2 (region aliases Wz_bf)
    k_bd<<<dim3(MM / 4), 256, 0, stream>>>(x, Wb, Wa, dtb, Alog, beta, decay);

    // conv writes vv into dead Wqkv_bf region (after GEMM1)
    k_conv_norm<<<dim3(MM * 64), 128, 0, stream>>>(qkv_bf, convw, qn, kn, vv);
    k_convbuf<<<dim3((B_ * QKV_ * 3 + 255) / 256), 256, 0, stream>>>(qkv_bf, cbuf);

    k_scan<<<dim3(256), 256, 0, stream>>>(qn, kn, vv, beta, decay, attn, S_out);

    // Wout cast AFTER scan (region aliases vv)
    k_cast<<<dim3((HID_ * VD_ / 4 + 255) / 256), 256, 0, stream>>>(Wout, Wout_bf, HID_ * VD_ / 4);

    k_rms_silu<<<dim3(MM * NV_ / 4), 256, 0, stream>>>(attn, z_bf, normw, ofuse);

    k_gemm_bt<0><<<dim3((MM / 128) * (HID_ / 128)), 256, 0, stream>>>(ofuse, Wout_bf, y_out, MM, HID_, VD_);
}

// Round 4
// 2273.511 us; speedup vs baseline: 1.2415x; 1.2415x over previous
//
#include <hip/hip_runtime.h>

#define B_ 2
#define T_ 2048
#define HID_ 2048
#define NK_ 16
#define DK_ 128
#define NV_ 32
#define DV_ 128
#define QKV_ 8192
#define VD_ 4096
#define QD_ 2048
#define MM (B_*T_)   // 4096
#define SV_ 256

typedef unsigned short u16;
typedef __attribute__((ext_vector_type(8))) unsigned short u16x8;
typedef __attribute__((ext_vector_type(8))) __bf16 bf16x8;
typedef __attribute__((ext_vector_type(4))) float f32x4;

__device__ inline u16 f2bf(float f) {
    unsigned int x = __float_as_uint(f);
    x += 0x7fffu + ((x >> 16) & 1u);   // round-to-nearest-even
    return (u16)(x >> 16);
}
__device__ inline float bf2f(u16 v) {
    return __uint_as_float(((unsigned int)v) << 16);
}

// ---------------- cast f32 -> bf16 (vectorized) ----------------
__global__ __launch_bounds__(256) void k_cast(const float* __restrict__ in,
                                              u16* __restrict__ out, int n4) {
    int i = blockIdx.x * 256 + threadIdx.x;
    if (i >= n4) return;
    float4 v = ((const float4*)in)[i];
    ((ushort4*)out)[i] = make_ushort4(f2bf(v.x), f2bf(v.y), f2bf(v.z), f2bf(v.w));
}

// ---------------- bf16 MFMA GEMM: C[M,N] = A[M,K] * B[N,K]^T ----------------
template <int OUT_BF16>
__global__ __launch_bounds__(256) void k_gemm_bt(const u16* __restrict__ A,
                                                 const u16* __restrict__ Bm,
                                                 void* __restrict__ Cv,
                                                 int M, int N, int K) {
    __shared__ __align__(16) u16 As[128 * 72];
    __shared__ __align__(16) u16 Bs[128 * 72];
    int nbx = N >> 7;
    int bx = blockIdx.x % nbx, by = blockIdx.x / nbx;
    int brow = by << 7, bcol = bx << 7;
    int tid = threadIdx.x, lane = tid & 63, w = tid >> 6;
    int wr = (w >> 1) << 6, wc = (w & 1) << 6;
    int srow = tid >> 1, scol = (tid & 1) << 5;

    const u16* ag = A + (size_t)(brow + srow) * K + scol;
    const u16* bg = Bm + (size_t)(bcol + srow) * K + scol;
    u16* asw = &As[srow * 72 + scol];
    u16* bsw = &Bs[srow * 72 + scol];

    f32x4 acc[4][4];
#pragma unroll
    for (int m = 0; m < 4; m++)
#pragma unroll
        for (int n = 0; n < 4; n++) acc[m][n] = (f32x4){0.f, 0.f, 0.f, 0.f};

    int lrow = lane & 15, khalf = (lane >> 4) * 8;

    for (int kt = 0; kt < K; kt += 64) {
#pragma unroll
        for (int u = 0; u < 4; ++u) {
            *(u16x8*)(asw + u * 8) = *(const u16x8*)(ag + kt + u * 8);
            *(u16x8*)(bsw + u * 8) = *(const u16x8*)(bg + kt + u * 8);
        }
        __syncthreads();
#pragma unroll
        for (int kk = 0; kk < 64; kk += 32) {
            bf16x8 af[4], bfr[4];
#pragma unroll
            for (int m = 0; m < 4; m++)
                af[m] = *(const bf16x8*)&As[(wr + m * 16 + lrow) * 72 + kk + khalf];
#pragma unroll
            for (int n = 0; n < 4; n++)
                bfr[n] = *(const bf16x8*)&Bs[(wc + n * 16 + lrow) * 72 + kk + khalf];
#pragma unroll
            for (int m = 0; m < 4; m++)
#pragma unroll
                for (int n = 0; n < 4; n++)
                    acc[m][n] = __builtin_amdgcn_mfma_f32_16x16x32_bf16(af[m], bfr[n], acc[m][n], 0, 0, 0);
        }
        __syncthreads();
    }
    int crow = brow + wr + (lane >> 4) * 4;
    int ccol = bcol + wc + lrow;
#pragma unroll
    for (int m = 0; m < 4; m++)
#pragma unroll
        for (int n = 0; n < 4; n++) {
            if (OUT_BF16) {
                u16* cp = (u16*)Cv + (size_t)(crow + m * 16) * N + ccol + n * 16;
#pragma unroll
                for (int r = 0; r < 4; r++) cp[(size_t)r * N] = f2bf(acc[m][n][r]);
            } else {
                float* cp = (float*)Cv + (size_t)(crow + m * 16) * N + ccol + n * 16;
#pragma unroll
                for (int r = 0; r < 4; r++) cp[(size_t)r * N] = acc[m][n][r];
            }
        }
}

// ---------------- beta / decay (fp32 exact) ----------------
__global__ __launch_bounds__(256) void k_bd(const float* __restrict__ x,
                                            const float* __restrict__ Wb,
                                            const float* __restrict__ Wa,
                                            const float* __restrict__ dtb,
                                            const float* __restrict__ Alog,
                                            float* __restrict__ beta,
                                            float* __restrict__ decay) {
    int h2 = threadIdx.x & 63;
    int bt = blockIdx.x * 4 + (threadIdx.x >> 6);
    const float* xr = x + (size_t)bt * HID_;
    const float* W = (h2 < NV_) ? (Wb + (size_t)h2 * HID_) : (Wa + (size_t)(h2 - NV_) * HID_);
    float acc = 0.f;
    for (int kk = 0; kk < HID_; kk += 4) {
        float4 xv = *(const float4*)&xr[kk];
        float4 wv = *(const float4*)&W[kk];
        acc += xv.x * wv.x + xv.y * wv.y + xv.z * wv.z + xv.w * wv.w;
    }
    if (h2 < NV_) {
        beta[(size_t)bt * NV_ + h2] = 1.f / (1.f + expf(-acc));
    } else {
        int hh = h2 - NV_;
        float a = acc + dtb[hh];
        float sp = (a > 20.f) ? a : log1pf(expf(a));
        decay[(size_t)bt * NV_ + hh] = expf(-sp * expf(Alog[hh]));
    }
}

// ---------------- causal depthwise conv (KC=4) + q/k l2norm ----------------
// qn/kn out: f32; vv out: bf16
__global__ __launch_bounds__(128) void k_conv_norm(const u16* __restrict__ qkv,
                                                   const float* __restrict__ conv_w,
                                                   float* __restrict__ qn,
                                                   float* __restrict__ kn,
                                                   u16* __restrict__ vv) {
    int g = blockIdx.x & 63;          // channel group of 128
    int bt = blockIdx.x >> 6;         // b*T + t
    int t = bt & (T_ - 1);
    int ch = (g << 7) + threadIdx.x;  // 0..8191
    float4 wv = *(const float4*)&conv_w[(size_t)ch << 2];
    const u16* col = qkv + (size_t)(bt - t) * QKV_ + ch;  // batch base
    float s = bf2f(col[(size_t)t * QKV_]) * wv.w;
    if (t >= 1) s += bf2f(col[(size_t)(t - 1) * QKV_]) * wv.z;
    if (t >= 2) s += bf2f(col[(size_t)(t - 2) * QKV_]) * wv.y;
    if (t >= 3) s += bf2f(col[(size_t)(t - 3) * QKV_]) * wv.x;

    if (g < 32) {
        float ss = s * s;
#pragma unroll
        for (int m = 1; m < 64; m <<= 1) ss += __shfl_xor(ss, m);
        __shared__ float red[2];
        if ((threadIdx.x & 63) == 0) red[threadIdx.x >> 6] = ss;
        __syncthreads();
        float tot = red[0] + red[1];
        float sc = 1.f / fmaxf(sqrtf(tot), 1e-12f);
        float o = s * sc;
        if (g < 16) qn[((size_t)bt * NK_ + g) * DK_ + threadIdx.x] = o;
        else        kn[((size_t)bt * NK_ + (g - 16)) * DK_ + threadIdx.x] = o;
    } else {
        vv[((size_t)bt * NV_ + (g - 32)) * DV_ + threadIdx.x] = f2bf(s);
    }
}

// ---------------- new_conv_buf output ----------------
__global__ __launch_bounds__(256) void k_convbuf(const u16* __restrict__ qkv,
                                                 float* __restrict__ ob) {
    int idx = blockIdx.x * 256 + threadIdx.x;
    if (idx >= B_ * QKV_ * 3) return;
    int jj = idx % 3;
    int d = (idx / 3) & (QKV_ - 1);
    int b = idx / (3 * QKV_);
    ob[idx] = bf2f(qkv[((size_t)b * T_ + (T_ - 3 + jj)) * QKV_ + d]);
}

// ---------------- q·k dot per (bt,h) ----------------
__global__ __launch_bounds__(256) void k_qk(const float* __restrict__ qn,
                                            const float* __restrict__ kn,
                                            float* __restrict__ qk) {
    int w = threadIdx.x >> 6, lane = threadIdx.x & 63;
    int bh = blockIdx.x * 4 + w;   // 0..MM*NK-1
    float2 q2 = *(const float2*)&qn[(size_t)bh * DK_ + lane * 2];
    float2 k2 = *(const float2*)&kn[(size_t)bh * DK_ + lane * 2];
    float s = q2.x * k2.x + q2.y * k2.y;
#pragma unroll
    for (int m = 1; m < 64; m <<= 1) s += __shfl_xor(s, m);
    if (lane == 0) qk[bh] = s;
}

// ---------------- recurrent delta-rule scan (barrier-free, reg-pipelined) ----
// grid 256 = (b=2, h=16, cg=8). Block 256: cl = tid>>3 (col 0..31), oi = tid&7
// (16-row slice). Depth-2 global->register prefetch; no LDS, no __syncthreads.
// Identity: o = q·S_new = decay*(q·S_old) + (q·k)*dv  (q·k precomputed).
#define SCAN_BODY(s, tcur)                                                    \
  {                                                                           \
    float kv[16], qv[16];                                                     \
    _Pragma("unroll") for (int u = 0; u < 4; ++u) {                           \
      *(f32x4*)&kv[u * 4] = skv##s[u];                                        \
      *(f32x4*)&qv[u * 4] = sqv##s[u];                                        \
    }                                                                         \
    float vval = bf2f(svv##s);                                                \
    float be = sbe##s, dc = sdc##s, qks = sqk##s;                             \
    if ((tcur) + 2 < T_) {                                                    \
      _Pragma("unroll") for (int u = 0; u < 4; ++u) {                         \
        skv##s[u] = *(const f32x4*)(kpre + u * 4);                            \
        sqv##s[u] = *(const f32x4*)(qpre + u * 4);                            \
      }                                                                       \
      svv##s = *vpre; sbe##s = *bpre; sdc##s = *dpre; sqk##s = *qkpre;        \
      kpre += NK_ * DK_; qpre += NK_ * DK_; vpre += NV_ * DV_;                \
      bpre += NV_; dpre += NV_; qkpre += NK_;                                 \
    }                                                                         \
    float gS[16];                                                             \
    _Pragma("unroll") for (int ii = 0; ii < 16; ++ii) gS[ii] = dc * S[ii];    \
    float a0 = 0, a1 = 0, a2 = 0, a3 = 0, b0 = 0, b1 = 0, b2 = 0, b3 = 0;    \
    _Pragma("unroll") for (int u = 0; u < 4; ++u) {                           \
      a0 = fmaf(kv[u*4+0], S[u*4+0], a0); b0 = fmaf(qv[u*4+0], S[u*4+0], b0); \
      a1 = fmaf(kv[u*4+1], S[u*4+1], a1); b1 = fmaf(qv[u*4+1], S[u*4+1], b1); \
      a2 = fmaf(kv[u*4+2], S[u*4+2], a2); b2 = fmaf(qv[u*4+2], S[u*4+2], b2); \
      a3 = fmaf(kv[u*4+3], S[u*4+3], a3); b3 = fmaf(qv[u*4+3], S[u*4+3], b3); \
    }                                                                         \
    float skp = (a0 + a1) + (a2 + a3);                                        \
    float qs = (b0 + b1) + (b2 + b3);                                         \
    skp += __shfl_xor(skp, 1); qs += __shfl_xor(qs, 1);                       \
    skp += __shfl_xor(skp, 2); qs += __shfl_xor(qs, 2);                       \
    skp += __shfl_xor(skp, 4); qs += __shfl_xor(qs, 4);                       \
    float dv = be * (vval - skp);                                             \
    float o = fmaf(qks, dv, dc * qs);                                         \
    _Pragma("unroll") for (int ii = 0; ii < 16; ++ii)                         \
      S[ii] = fmaf(kv[ii], dv, gS[ii]);                                       \
    if (oi == 0) *ao = o;                                                     \
    ao += NV_ * DV_;                                                          \
  }

__global__ __launch_bounds__(256, 1) void k_scan(const float* __restrict__ qn,
                                                 const float* __restrict__ kn,
                                                 const u16* __restrict__ vv,
                                                 const float* __restrict__ beta,
                                                 const float* __restrict__ decay,
                                                 const float* __restrict__ qk,
                                                 float* __restrict__ attn,
                                                 float* __restrict__ Sout) {
    int cg = blockIdx.x & 7;
    int h = (blockIdx.x >> 3) & 15;
    int b = blockIdx.x >> 7;
    int tid = threadIdx.x;
    int cl = tid >> 3;      // 0..31 column in group
    int oi = tid & 7;       // 0..7  16-row slice
    int i0 = oi << 4;
    int c = (cg << 5) + cl; // 0..255 state column
    int p = c >> 7;         // block-uniform
    int j = c & 127;
    int nv = (h << 1) + p;
    const size_t bT = (size_t)b * T_;

    float S[16];
#pragma unroll
    for (int ii = 0; ii < 16; ++ii) S[ii] = 0.f;

    const float* kbase = kn + ((bT)*NK_ + h) * DK_ + i0;
    const float* qbase = qn + ((bT)*NK_ + h) * DK_ + i0;
    const u16*   vbase = vv + ((bT)*NV_ + nv) * DV_ + j;
    const float* bbase = beta + (bT)*NV_ + nv;
    const float* dbase = decay + (bT)*NV_ + nv;
    const float* qkbase = qk + (bT)*NK_ + h;
    float* ao = attn + ((bT)*NV_ + nv) * DV_ + j;

    // prime slots 0 (t=0) and 1 (t=1)
    f32x4 skv0[4], sqv0[4], skv1[4], sqv1[4];
    u16 svv0, svv1;
    float sbe0, sdc0, sqk0, sbe1, sdc1, sqk1;
#pragma unroll
    for (int u = 0; u < 4; ++u) {
        skv0[u] = *(const f32x4*)(kbase + u * 4);
        sqv0[u] = *(const f32x4*)(qbase + u * 4);
        skv1[u] = *(const f32x4*)(kbase + NK_ * DK_ + u * 4);
        sqv1[u] = *(const f32x4*)(qbase + NK_ * DK_ + u * 4);
    }
    svv0 = vbase[0]; svv1 = vbase[NV_ * DV_];
    sbe0 = bbase[0]; sbe1 = bbase[NV_];
    sdc0 = dbase[0]; sdc1 = dbase[NV_];
    sqk0 = qkbase[0]; sqk1 = qkbase[NK_];

    // prefetch pointers at t=2
    const float* kpre = kbase + 2 * NK_ * DK_;
    const float* qpre = qbase + 2 * NK_ * DK_;
    const u16*   vpre = vbase + 2 * NV_ * DV_;
    const float* bpre = bbase + 2 * NV_;
    const float* dpre = dbase + 2 * NV_;
    const float* qkpre = qkbase + 2 * NK_;

    for (int t = 0; t < T_; t += 2) {
        SCAN_BODY(0, t)
        SCAN_BODY(1, t + 1)
    }

#pragma unroll
    for (int ii = 0; ii < 16; ++ii)
        Sout[(((size_t)b * NK_ + h) * DK_ + (i0 + ii)) * SV_ + c] = S[ii];
}

// ---------------- RMSNorm + silu(z) gate -> bf16 ----------------
__global__ __launch_bounds__(256) void k_rms_silu(const float* __restrict__ attn,
                                                  const u16* __restrict__ z,
                                                  const float* __restrict__ norm_w,
                                                  u16* __restrict__ ofuse) {
    int w = threadIdx.x >> 6, lane = threadIdx.x & 63;
    size_t hm = (size_t)blockIdx.x * 4 + w;  // (b*T+t)*NV + nv
    const float* row = attn + hm * DV_;
    float2 v = *(const float2*)&row[lane * 2];
    float ss = v.x * v.x + v.y * v.y;
#pragma unroll
    for (int m = 1; m < 64; m <<= 1) ss += __shfl_xor(ss, m);
    float rms = rsqrtf(ss * (1.f / DV_) + 1e-6f);
    float2 nw = *(const float2*)&norm_w[lane * 2];
    size_t idx = hm * DV_ + lane * 2;
    ushort2 zv2 = *(const ushort2*)&z[idx];
    float z0 = bf2f(zv2.x), z1 = bf2f(zv2.y);
    float s0 = z0 / (1.f + expf(-z0));
    float s1 = z1 / (1.f + expf(-z1));
    *(ushort2*)&ofuse[idx] = make_ushort2(f2bf(v.x * rms * nw.x * s0),
                                          f2bf(v.y * rms * nw.y * s1));
}

extern "C" void kernel_launch(void* const* d_in, const int* in_sizes, int n_in,
                              void* d_out, int out_size, void* d_ws, size_t ws_size,
                              hipStream_t stream) {
    const float* x     = (const float*)d_in[0];
    const float* Wqkv  = (const float*)d_in[1];
    const float* Wz    = (const float*)d_in[2];
    const float* Wb    = (const float*)d_in[3];
    const float* Wa    = (const float*)d_in[4];
    const float* convw = (const float*)d_in[5];
    const float* dtb   = (const float*)d_in[6];
    const float* Alog  = (const float*)d_in[7];
    const float* normw = (const float*)d_in[8];
    const float* Wout  = (const float*)d_in[9];
    float* out = (float*)d_out;

    // ---- workspace plan (224 MB peak), lifetime-aliased ----
    // [0,16)    x_bf (casts->GEMM2); then beta[0,.5M) decay[.5M,1M) qk[1M,1.25M)
    // [16,48)   Wqkv_bf (cast->GEMM1); then vv bf16 [16,32) (conv->scan)
    // [48,64)   Wz_bf (cast->GEMM2); then Wout_bf (cast->GEMM3)
    // [64,128)  qkv_bf (GEMM1->conv/convbuf); then attn f32 (scan->rms)
    // [128,160) z_bf (GEMM2->rms)
    // [160,192) qn f32 (conv->qk/scan); then ofuse (rms->GEMM3)
    // [192,224) kn f32 (conv->qk/scan)
    char* ws = (char*)d_ws;
    u16*   x_bf    = (u16*)(ws);
    float* beta    = (float*)(ws);
    float* decay   = (float*)(ws + ((size_t)1 << 19));
    float* qk      = (float*)(ws + ((size_t)1 << 20));
    u16*   Wqkv_bf = (u16*)(ws + ((size_t)16 << 20));
    u16*   vv      = (u16*)(ws + ((size_t)16 << 20));
    u16*   Wz_bf   = (u16*)(ws + ((size_t)48 << 20));
    u16*   Wout_bf = (u16*)(ws + ((size_t)48 << 20));
    u16*   qkv_bf  = (u16*)(ws + ((size_t)64 << 20));
    float* attn    = (float*)(ws + ((size_t)64 << 20));
    u16*   z_bf    = (u16*)(ws + ((size_t)128 << 20));
    float* qn      = (float*)(ws + ((size_t)160 << 20));
    u16*   ofuse   = (u16*)(ws + ((size_t)160 << 20));
    float* kn      = (float*)(ws + ((size_t)192 << 20));

    float* y_out = out;
    float* S_out = out + (size_t)MM * HID_;
    float* cbuf  = S_out + (size_t)B_ * NK_ * DK_ * SV_;

    k_cast<<<dim3((MM * HID_ / 4 + 255) / 256), 256, 0, stream>>>(x, x_bf, MM * HID_ / 4);
    k_cast<<<dim3((QKV_ * HID_ / 4 + 255) / 256), 256, 0, stream>>>(Wqkv, Wqkv_bf, QKV_ * HID_ / 4);
    k_cast<<<dim3((VD_ * HID_ / 4 + 255) / 256), 256, 0, stream>>>(Wz, Wz_bf, VD_ * HID_ / 4);

    k_gemm_bt<1><<<dim3((MM / 128) * (QKV_ / 128)), 256, 0, stream>>>(x_bf, Wqkv_bf, qkv_bf, MM, QKV_, HID_);
    k_gemm_bt<1><<<dim3((MM / 128) * (VD_ / 128)), 256, 0, stream>>>(x_bf, Wz_bf, z_bf, MM, VD_, HID_);

    // after GEMM2: Wz_bf dead -> Wout cast; x_bf dead -> beta/decay
    k_cast<<<dim3((HID_ * VD_ / 4 + 255) / 256), 256, 0, stream>>>(Wout, Wout_bf, HID_ * VD_ / 4);
    k_bd<<<dim3(MM / 4), 256, 0, stream>>>(x, Wb, Wa, dtb, Alog, beta, decay);

    // after GEMM1: Wqkv_bf dead -> vv
    k_conv_norm<<<dim3(MM * 64), 128, 0, stream>>>(qkv_bf, convw, qn, kn, vv);
    k_convbuf<<<dim3((B_ * QKV_ * 3 + 255) / 256), 256, 0, stream>>>(qkv_bf, cbuf);

    k_qk<<<dim3(MM * NK_ / 4), 256, 0, stream>>>(qn, kn, qk);

    k_scan<<<dim3(256), 256, 0, stream>>>(qn, kn, vv, beta, decay, qk, attn, S_out);

    k_rms_silu<<<dim3(MM * NV_ / 4), 256, 0, stream>>>(attn, z_bf, normw, ofuse);

    k_gemm_bt<0><<<dim3((MM / 128) * (HID_ / 128)), 256, 0, stream>>>(ofuse, Wout_bf, y_out, MM, HID_, VD_);
}